// Round 2
// baseline (747.208 us; speedup 1.0000x reference)
//
#include <hip/hip_runtime.h>
#include <math.h>

// Problem constants
constexpr int BATCH = 16384;
constexpr int IND   = 2048;   // INPUT
constexpr int HID   = 32;     // HIDDEN
constexpr int OUTD  = 512;    // OUTPUT

// Accumulator region (in d_ws, after act): corr1 + corr2 + xsum + actsum + outsum
constexpr int ZERO_ELEMS = IND * HID + HID * OUTD + IND + HID + OUTD;  // 84512

// ---------------------------------------------------------------------------
// K0: zero the accumulator region. Plain-store kernel instead of
// hipMemsetAsync: memset during stream capture is the one non-kernel op in
// the round-1 pipeline and the prime suspect for the post-timing divergence
// (mis-captured node => replays see corrupted/unzeroed accumulators).
// ---------------------------------------------------------------------------
__global__ __launch_bounds__(256) void k_zero(float4* __restrict__ p, int n4) {
  const int i = blockIdx.x * 256 + threadIdx.x;
  if (i < n4) p[i] = float4{0.f, 0.f, 0.f, 0.f};
}

// ---------------------------------------------------------------------------
// K1: act[b,h] = relu(sum_k x[b,k] * w1[h,k]);  actsum[h] += sum_b act[b,h]
// block = 256 threads = 32 h-lanes x 8 groups; each thread handles 4 b rows.
// grid = 16384/32 = 512 blocks (2 blocks/CU).
// ---------------------------------------------------------------------------
__global__ __launch_bounds__(256, 2) void k_act(
    const float* __restrict__ x, const float* __restrict__ w1,
    float* __restrict__ act, float* __restrict__ actsum) {
  const int tid = threadIdx.x;
  const int h = tid & 31;
  const int g = tid >> 5;                  // 0..7
  const int b0 = blockIdx.x * 32 + g * 4;  // 4 rows per thread

  const float4* __restrict__ w1p = (const float4*)(w1 + (size_t)h * IND);
  const float4* __restrict__ xp  = (const float4*)x;

  float acc0 = 0.f, acc1 = 0.f, acc2 = 0.f, acc3 = 0.f;
#pragma unroll 4
  for (int k4 = 0; k4 < IND / 4; ++k4) {
    float4 w  = w1p[k4];
    float4 x0 = xp[(size_t)(b0 + 0) * (IND / 4) + k4];
    float4 x1 = xp[(size_t)(b0 + 1) * (IND / 4) + k4];
    float4 x2 = xp[(size_t)(b0 + 2) * (IND / 4) + k4];
    float4 x3 = xp[(size_t)(b0 + 3) * (IND / 4) + k4];
    acc0 += x0.x * w.x + x0.y * w.y + x0.z * w.z + x0.w * w.w;
    acc1 += x1.x * w.x + x1.y * w.y + x1.z * w.z + x1.w * w.w;
    acc2 += x2.x * w.x + x2.y * w.y + x2.z * w.z + x2.w * w.w;
    acc3 += x3.x * w.x + x3.y * w.y + x3.z * w.z + x3.w * w.w;
  }

  float a0 = acc0 > 0.f ? acc0 : 0.f;
  float a1 = acc1 > 0.f ? acc1 : 0.f;
  float a2 = acc2 > 0.f ? acc2 : 0.f;
  float a3 = acc3 > 0.f ? acc3 : 0.f;
  act[(size_t)(b0 + 0) * HID + h] = a0;
  act[(size_t)(b0 + 1) * HID + h] = a1;
  act[(size_t)(b0 + 2) * HID + h] = a2;
  act[(size_t)(b0 + 3) * HID + h] = a3;

  __shared__ float red[256];
  red[tid] = a0 + a1 + a2 + a3;
  __syncthreads();
  if (tid < 32) {
    float s = 0.f;
#pragma unroll
    for (int gg = 0; gg < 8; ++gg) s += red[tid + 32 * gg];
    atomicAdd(actsum + tid, s);
  }
}

// ---------------------------------------------------------------------------
// K2: corr1[i,j] = sum_b x[b,i]*act[b,j];  xsum[i] = sum_b x[b,i]
// block = 256 threads; thread owns i = i0 + 2*tid (+1) and all 32 j (64 accs).
// grid = 4 i-tiles x 128 b-chunks (128 b each) = 512 blocks.
// act chunk staged in LDS; broadcast reads (conflict-free).
// ---------------------------------------------------------------------------
__global__ __launch_bounds__(256, 2) void k_corr1(
    const float* __restrict__ x, const float* __restrict__ act,
    float* __restrict__ corr1, float* __restrict__ xsum) {
  const int tid = threadIdx.x;
  const int i0 = (blockIdx.x & 3) * 512;
  const int b0 = (blockIdx.x >> 2) * 128;

  __shared__ float act_s[128][HID];
  {
    const float4* ag = (const float4*)(act + (size_t)b0 * HID);
    float4* as = (float4*)(&act_s[0][0]);
#pragma unroll
    for (int q = 0; q < 4; ++q) as[tid + 256 * q] = ag[tid + 256 * q];
  }
  __syncthreads();

  const float2* __restrict__ xp = (const float2*)x;
  const int i2 = i0 / 2 + tid;

  float acc0[HID], acc1[HID];
#pragma unroll
  for (int j = 0; j < HID; ++j) { acc0[j] = 0.f; acc1[j] = 0.f; }
  float xs0 = 0.f, xs1 = 0.f;

#pragma unroll 2
  for (int b = 0; b < 128; ++b) {
    float2 xv = xp[(size_t)(b0 + b) * (IND / 2) + i2];
    xs0 += xv.x; xs1 += xv.y;
#pragma unroll
    for (int q = 0; q < 8; ++q) {
      float4 a = ((const float4*)(&act_s[b][0]))[q];
      acc0[4 * q + 0] += xv.x * a.x; acc0[4 * q + 1] += xv.x * a.y;
      acc0[4 * q + 2] += xv.x * a.z; acc0[4 * q + 3] += xv.x * a.w;
      acc1[4 * q + 0] += xv.y * a.x; acc1[4 * q + 1] += xv.y * a.y;
      acc1[4 * q + 2] += xv.y * a.z; acc1[4 * q + 3] += xv.y * a.w;
    }
  }

  const int ia = i0 + 2 * tid;
#pragma unroll
  for (int j = 0; j < HID; ++j) {
    atomicAdd(corr1 + (size_t)ia * HID + j, acc0[j]);
    atomicAdd(corr1 + (size_t)(ia + 1) * HID + j, acc1[j]);
  }
  atomicAdd(xsum + ia, xs0);
  atomicAdd(xsum + ia + 1, xs1);
}

// ---------------------------------------------------------------------------
// K3: out[b,o] = sigmoid(sum_h act[b,h]*w2[o,h]) - 0.4
//     corr2[h,o] += sum_b act[b,h]*out[b,o];  outsum[o] += sum_b out[b,o]
// thread owns one o (w2 row + corr2 column in registers).
// grid = 2 o-tiles x 256 b-chunks (64 b each) = 512 blocks.
// ---------------------------------------------------------------------------
__global__ __launch_bounds__(256, 2) void k_fwd2(
    const float* __restrict__ act, const float* __restrict__ w2,
    float* __restrict__ out, float* __restrict__ corr2,
    float* __restrict__ outsum) {
  const int tid = threadIdx.x;
  const int o = (blockIdx.x & 1) * 256 + tid;
  const int b0 = (blockIdx.x >> 1) * 64;

  __shared__ float act_s[64][HID];
  {
    const float4* ag = (const float4*)(act + (size_t)b0 * HID);
    float4* as = (float4*)(&act_s[0][0]);
    as[tid] = ag[tid];
    as[tid + 256] = ag[tid + 256];
  }

  float w2r[HID];
#pragma unroll
  for (int q = 0; q < 8; ++q) {
    float4 w = ((const float4*)(w2 + (size_t)o * HID))[q];
    w2r[4 * q + 0] = w.x; w2r[4 * q + 1] = w.y;
    w2r[4 * q + 2] = w.z; w2r[4 * q + 3] = w.w;
  }

  float acc[HID];
#pragma unroll
  for (int h = 0; h < HID; ++h) acc[h] = 0.f;
  float osum = 0.f;

  __syncthreads();
  for (int b = 0; b < 64; ++b) {
    float ar[HID];
#pragma unroll
    for (int q = 0; q < 8; ++q) {
      float4 a = ((const float4*)(&act_s[b][0]))[q];
      ar[4 * q + 0] = a.x; ar[4 * q + 1] = a.y;
      ar[4 * q + 2] = a.z; ar[4 * q + 3] = a.w;
    }
    float z = 0.f;
#pragma unroll
    for (int h = 0; h < HID; ++h) z += ar[h] * w2r[h];
    float ov = 1.0f / (1.0f + __expf(-z)) - 0.4f;
    out[(size_t)(b0 + b) * OUTD + o] = ov;
    osum += ov;
#pragma unroll
    for (int h = 0; h < HID; ++h) acc[h] += ar[h] * ov;
  }

#pragma unroll
  for (int h = 0; h < HID; ++h) atomicAdd(corr2 + (size_t)h * OUTD + o, acc[h]);
  atomicAdd(outsum + o, osum);
}

// ---------------------------------------------------------------------------
// K4: w1_new[h,i] = (w1[h,i] + dw1T[i,h]) / ||row h||_2
// dw1T[i,h] = B*c1[i,h,3] + c1[i,h,0]*corr1[i,h] + c1[i,h,1]*xsum[i]
//           + c1[i,h,2]*actsum[h];  c1 row index = i*32+h
// one block per h row; 256 threads x 8 i each.
// ---------------------------------------------------------------------------
__global__ __launch_bounds__(256) void k_w1(
    const float* __restrict__ w1, const float* __restrict__ heb,
    const float* __restrict__ corr1, const float* __restrict__ xsum,
    const float* __restrict__ actsum, float* __restrict__ w1out) {
  const int h = blockIdx.x;
  const int tid = threadIdx.x;
  const float ash = actsum[h];
  const float4* heb4 = (const float4*)heb;

  float val[8];
  float ss = 0.f;
#pragma unroll
  for (int r = 0; r < 8; ++r) {
    const int i = tid + 256 * r;
    float4 c = heb4[(size_t)i * HID + h];
    float v = w1[(size_t)h * IND + i] + 16384.0f * c.w +
              c.x * corr1[(size_t)i * HID + h] + c.y * xsum[i] + c.z * ash;
    val[r] = v;
    ss += v * v;
  }

  __shared__ float red[256];
  red[tid] = ss;
  __syncthreads();
  for (int s = 128; s > 0; s >>= 1) {
    if (tid < s) red[tid] += red[tid + s];
    __syncthreads();
  }
  const float inv = 1.0f / sqrtf(red[0]);
#pragma unroll
  for (int r = 0; r < 8; ++r) {
    const int i = tid + 256 * r;
    w1out[(size_t)h * IND + i] = val[r] * inv;
  }
}

// ---------------------------------------------------------------------------
// K5: w2_new[o,h] = (w2[o,h] + dw2T[h,o]) / ||row o||_2
// dw2T[h,o] = B*c2[h,o,3] + c2[h,o,0]*corr2[h,o] + c2[h,o,1]*actsum[h]
//           + c2[h,o,2]*outsum[o];  c2 row index = 65536 + h*512 + o
// one thread per o row. grid = 2 x 256 threads.
// ---------------------------------------------------------------------------
__global__ __launch_bounds__(256) void k_w2(
    const float* __restrict__ w2, const float* __restrict__ heb,
    const float* __restrict__ corr2, const float* __restrict__ actsum,
    const float* __restrict__ outsum, float* __restrict__ w2out) {
  const int o = blockIdx.x * 256 + threadIdx.x;
  const float oso = outsum[o];
  const float4* heb4 = (const float4*)heb;

  float val[HID];
  float ss = 0.f;
#pragma unroll
  for (int h = 0; h < HID; ++h) {
    float4 c = heb4[(size_t)(HID * IND) + (size_t)h * OUTD + o];
    float v = w2[(size_t)o * HID + h] + 16384.0f * c.w +
              c.x * corr2[(size_t)h * OUTD + o] + c.y * actsum[h] + c.z * oso;
    val[h] = v;
    ss += v * v;
  }
  const float inv = 1.0f / sqrtf(ss);
#pragma unroll
  for (int h = 0; h < HID; ++h) w2out[(size_t)o * HID + h] = val[h] * inv;
}

// ---------------------------------------------------------------------------
extern "C" void kernel_launch(void* const* d_in, const int* in_sizes, int n_in,
                              void* d_out, int out_size, void* d_ws,
                              size_t ws_size, hipStream_t stream) {
  const float* x   = (const float*)d_in[0];   // [16384, 2048]
  const float* w1  = (const float*)d_in[1];   // [32, 2048]
  const float* w2  = (const float*)d_in[2];   // [512, 32]
  const float* heb = (const float*)d_in[3];   // [81920, 4]

  float* out = (float*)d_out;                 // [16384, 512]
  float* w1o = out + (size_t)BATCH * OUTD;    // [32, 2048]
  float* w2o = w1o + (size_t)HID * IND;       // [512, 32]

  float* ws     = (float*)d_ws;
  float* act    = ws;                                  // 16384*32 = 524288
  float* corr1  = act + (size_t)BATCH * HID;           // 2048*32  = 65536
  float* corr2  = corr1 + (size_t)IND * HID;           // 32*512   = 16384
  float* xsum   = corr2 + (size_t)HID * OUTD;          // 2048
  float* actsum = xsum + IND;                          // 32
  float* outsum = actsum + HID;                        // 512

  // zero the accumulator region via a kernel (NOT hipMemsetAsync — avoid any
  // non-kernel node in the captured graph); ws is not re-poisoned between
  // replays, so this must run every call.
  const int n4 = ZERO_ELEMS / 4;  // 84512 / 4 = 21128 float4s
  k_zero <<<(n4 + 255) / 256, 256, 0, stream>>>((float4*)corr1, n4);

  k_act  <<<512, 256, 0, stream>>>(x, w1, act, actsum);
  k_corr1<<<512, 256, 0, stream>>>(x, act, corr1, xsum);
  k_fwd2 <<<512, 256, 0, stream>>>(act, w2, out, corr2, outsum);
  k_w1   <<<32, 256, 0, stream>>>(w1, heb, corr1, xsum, actsum, w1o);
  k_w2   <<<2, 256, 0, stream>>>(w2, heb, corr2, actsum, outsum, w2o);
}

// Round 3
// 738.012 us; speedup vs baseline: 1.0125x; 1.0125x over previous
//
#include <hip/hip_runtime.h>
#include <math.h>

// Problem constants
constexpr int BATCH = 16384;
constexpr int IND   = 2048;   // INPUT
constexpr int HID   = 32;     // HIDDEN
constexpr int OUTD  = 512;    // OUTPUT

// Accumulator region (in d_ws, after act): corr1 + corr2 + xsum + actsum + outsum
constexpr int ZERO_ELEMS = IND * HID + HID * OUTD + IND + HID + OUTD;  // 84512

// FMA helpers on named float4s (no arrays -> no scratch spill possible)
#define UPD4(C, A, S)                 \
  (C).x = fmaf((S), (A).x, (C).x);    \
  (C).y = fmaf((S), (A).y, (C).y);    \
  (C).z = fmaf((S), (A).z, (C).z);    \
  (C).w = fmaf((S), (A).w, (C).w);

#define DOT4(Z, A, W)                 \
  (Z) = fmaf((A).x, (W).x, (Z));      \
  (Z) = fmaf((A).y, (W).y, (Z));      \
  (Z) = fmaf((A).z, (W).z, (Z));      \
  (Z) = fmaf((A).w, (W).w, (Z));

#define ATO4(P, C)                    \
  atomicAdd((P) + 0, (C).x);          \
  atomicAdd((P) + 1, (C).y);          \
  atomicAdd((P) + 2, (C).z);          \
  atomicAdd((P) + 3, (C).w);

// ---------------------------------------------------------------------------
// K0: zero the accumulator region (kernel, not hipMemsetAsync: keeps the
// captured graph all-kernel; round-1 memset node diverged under replay).
// ---------------------------------------------------------------------------
__global__ __launch_bounds__(256) void k_zero(float4* __restrict__ p, int n4) {
  const int i = blockIdx.x * 256 + threadIdx.x;
  if (i < n4) p[i] = float4{0.f, 0.f, 0.f, 0.f};
}

// ---------------------------------------------------------------------------
// K1: act[b,h] = relu(sum_k x[b,k] * w1[h,k]);  actsum[h] += sum_b act[b,h]
// block = 256 threads = 32 h-lanes x 8 groups; each thread handles 4 b rows.
// grid = 512 blocks. Named scalar accumulators only.
// ---------------------------------------------------------------------------
__global__ __launch_bounds__(256, 2) void k_act(
    const float* __restrict__ x, const float* __restrict__ w1,
    float* __restrict__ act, float* __restrict__ actsum) {
  const int tid = threadIdx.x;
  const int h = tid & 31;
  const int g = tid >> 5;                  // 0..7
  const int b0 = blockIdx.x * 32 + g * 4;  // 4 rows per thread

  const float4* __restrict__ w1p = (const float4*)(w1 + (size_t)h * IND);
  const float4* __restrict__ xp  = (const float4*)x;

  float acc0 = 0.f, acc1 = 0.f, acc2 = 0.f, acc3 = 0.f;
#pragma unroll 4
  for (int k4 = 0; k4 < IND / 4; ++k4) {
    float4 w  = w1p[k4];
    float4 x0 = xp[(size_t)(b0 + 0) * (IND / 4) + k4];
    float4 x1 = xp[(size_t)(b0 + 1) * (IND / 4) + k4];
    float4 x2 = xp[(size_t)(b0 + 2) * (IND / 4) + k4];
    float4 x3 = xp[(size_t)(b0 + 3) * (IND / 4) + k4];
    DOT4(acc0, x0, w);
    DOT4(acc1, x1, w);
    DOT4(acc2, x2, w);
    DOT4(acc3, x3, w);
  }

  float a0 = acc0 > 0.f ? acc0 : 0.f;
  float a1 = acc1 > 0.f ? acc1 : 0.f;
  float a2 = acc2 > 0.f ? acc2 : 0.f;
  float a3 = acc3 > 0.f ? acc3 : 0.f;
  act[(size_t)(b0 + 0) * HID + h] = a0;
  act[(size_t)(b0 + 1) * HID + h] = a1;
  act[(size_t)(b0 + 2) * HID + h] = a2;
  act[(size_t)(b0 + 3) * HID + h] = a3;

  __shared__ float red[256];
  red[tid] = a0 + a1 + a2 + a3;
  __syncthreads();
  if (tid < 32) {
    float s = 0.f;
#pragma unroll
    for (int gg = 0; gg < 8; ++gg) s += red[tid + 32 * gg];
    atomicAdd(actsum + tid, s);
  }
}

// ---------------------------------------------------------------------------
// K2: corr1[i,j] = sum_b x[b,i]*act[b,j];  xsum[i] = sum_b x[b,i]
// block = 256 threads; thread owns i = i0+2*tid (+1), all 32 j.
// 16 NAMED float4 accumulators (round-2 array version spilled to scratch:
// VGPR=52, 264 MB HBM writes, 471 us @ 3% VALU — L2-bound on spill traffic).
// grid = 4 i-tiles x 128 b-chunks = 512 blocks.
// ---------------------------------------------------------------------------
__global__ __launch_bounds__(256, 2) void k_corr1(
    const float* __restrict__ x, const float* __restrict__ act,
    float* __restrict__ corr1, float* __restrict__ xsum) {
  const int tid = threadIdx.x;
  const int i0 = (blockIdx.x & 3) * 512;
  const int b0 = (blockIdx.x >> 2) * 128;

  __shared__ float act_s[128][HID];
  {
    const float4* ag = (const float4*)(act + (size_t)b0 * HID);
    float4* as = (float4*)(&act_s[0][0]);
#pragma unroll
    for (int q = 0; q < 4; ++q) as[tid + 256 * q] = ag[tid + 256 * q];
  }
  __syncthreads();

  const float2* __restrict__ xp = (const float2*)x;
  const int i2 = i0 / 2 + tid;

  float4 c00{0,0,0,0}, c01{0,0,0,0}, c02{0,0,0,0}, c03{0,0,0,0};
  float4 c04{0,0,0,0}, c05{0,0,0,0}, c06{0,0,0,0}, c07{0,0,0,0};
  float4 c10{0,0,0,0}, c11{0,0,0,0}, c12{0,0,0,0}, c13{0,0,0,0};
  float4 c14{0,0,0,0}, c15{0,0,0,0}, c16{0,0,0,0}, c17{0,0,0,0};
  float xs0 = 0.f, xs1 = 0.f;

#pragma unroll 2
  for (int b = 0; b < 128; ++b) {
    float2 xv = xp[(size_t)(b0 + b) * (IND / 2) + i2];
    xs0 += xv.x; xs1 += xv.y;
    const float4* ar = (const float4*)(&act_s[b][0]);
    float4 a0 = ar[0], a1 = ar[1], a2 = ar[2], a3 = ar[3];
    float4 a4 = ar[4], a5 = ar[5], a6 = ar[6], a7 = ar[7];
    UPD4(c00, a0, xv.x); UPD4(c01, a1, xv.x); UPD4(c02, a2, xv.x); UPD4(c03, a3, xv.x);
    UPD4(c04, a4, xv.x); UPD4(c05, a5, xv.x); UPD4(c06, a6, xv.x); UPD4(c07, a7, xv.x);
    UPD4(c10, a0, xv.y); UPD4(c11, a1, xv.y); UPD4(c12, a2, xv.y); UPD4(c13, a3, xv.y);
    UPD4(c14, a4, xv.y); UPD4(c15, a5, xv.y); UPD4(c16, a6, xv.y); UPD4(c17, a7, xv.y);
  }

  const int ia = i0 + 2 * tid;
  float* r0 = corr1 + (size_t)ia * HID;
  float* r1 = corr1 + (size_t)(ia + 1) * HID;
  ATO4(r0 + 0,  c00); ATO4(r0 + 4,  c01); ATO4(r0 + 8,  c02); ATO4(r0 + 12, c03);
  ATO4(r0 + 16, c04); ATO4(r0 + 20, c05); ATO4(r0 + 24, c06); ATO4(r0 + 28, c07);
  ATO4(r1 + 0,  c10); ATO4(r1 + 4,  c11); ATO4(r1 + 8,  c12); ATO4(r1 + 12, c13);
  ATO4(r1 + 16, c14); ATO4(r1 + 20, c15); ATO4(r1 + 24, c16); ATO4(r1 + 28, c17);
  atomicAdd(xsum + ia, xs0);
  atomicAdd(xsum + ia + 1, xs1);
}

// ---------------------------------------------------------------------------
// K3: out[b,o] = sigmoid(sum_h act[b,h]*w2[o,h]) - 0.4
//     corr2[h,o] += sum_b act[b,h]*out[b,o];  outsum[o] += sum_b out[b,o]
// thread owns one o. NAMED float4 regs for w2 row / corr2 accumulators
// (round-2 arrays risked the same scratch spill as k_corr1).
// grid = 2 o-tiles x 256 b-chunks (64 b) = 512 blocks.
// ---------------------------------------------------------------------------
__global__ __launch_bounds__(256, 2) void k_fwd2(
    const float* __restrict__ act, const float* __restrict__ w2,
    float* __restrict__ out, float* __restrict__ corr2,
    float* __restrict__ outsum) {
  const int tid = threadIdx.x;
  const int o = (blockIdx.x & 1) * 256 + tid;
  const int b0 = (blockIdx.x >> 1) * 64;

  __shared__ float act_s[64][HID];
  {
    const float4* ag = (const float4*)(act + (size_t)b0 * HID);
    float4* as = (float4*)(&act_s[0][0]);
    as[tid] = ag[tid];
    as[tid + 256] = ag[tid + 256];
  }

  const float4* w2p = (const float4*)(w2 + (size_t)o * HID);
  float4 w0 = w2p[0], w1r = w2p[1], w2r_ = w2p[2], w3 = w2p[3];
  float4 w4 = w2p[4], w5 = w2p[5], w6 = w2p[6], w7 = w2p[7];

  float4 s0{0,0,0,0}, s1{0,0,0,0}, s2{0,0,0,0}, s3{0,0,0,0};
  float4 s4{0,0,0,0}, s5{0,0,0,0}, s6{0,0,0,0}, s7{0,0,0,0};
  float osum = 0.f;

  __syncthreads();
  for (int b = 0; b < 64; ++b) {
    const float4* ar = (const float4*)(&act_s[b][0]);
    float4 a0 = ar[0], a1 = ar[1], a2 = ar[2], a3 = ar[3];
    float4 a4 = ar[4], a5 = ar[5], a6 = ar[6], a7 = ar[7];
    float z = 0.f;
    DOT4(z, a0, w0); DOT4(z, a1, w1r); DOT4(z, a2, w2r_); DOT4(z, a3, w3);
    DOT4(z, a4, w4); DOT4(z, a5, w5);  DOT4(z, a6, w6);   DOT4(z, a7, w7);
    float ov = 1.0f / (1.0f + __expf(-z)) - 0.4f;
    out[(size_t)(b0 + b) * OUTD + o] = ov;
    osum += ov;
    UPD4(s0, a0, ov); UPD4(s1, a1, ov); UPD4(s2, a2, ov); UPD4(s3, a3, ov);
    UPD4(s4, a4, ov); UPD4(s5, a5, ov); UPD4(s6, a6, ov); UPD4(s7, a7, ov);
  }

  // corr2 is [h][OUTD]; thread owns column o -> stride OUTD between h's.
  float* c = corr2 + o;
  atomicAdd(c + 0 * OUTD,  s0.x); atomicAdd(c + 1 * OUTD,  s0.y);
  atomicAdd(c + 2 * OUTD,  s0.z); atomicAdd(c + 3 * OUTD,  s0.w);
  atomicAdd(c + 4 * OUTD,  s1.x); atomicAdd(c + 5 * OUTD,  s1.y);
  atomicAdd(c + 6 * OUTD,  s1.z); atomicAdd(c + 7 * OUTD,  s1.w);
  atomicAdd(c + 8 * OUTD,  s2.x); atomicAdd(c + 9 * OUTD,  s2.y);
  atomicAdd(c + 10 * OUTD, s2.z); atomicAdd(c + 11 * OUTD, s2.w);
  atomicAdd(c + 12 * OUTD, s3.x); atomicAdd(c + 13 * OUTD, s3.y);
  atomicAdd(c + 14 * OUTD, s3.z); atomicAdd(c + 15 * OUTD, s3.w);
  atomicAdd(c + 16 * OUTD, s4.x); atomicAdd(c + 17 * OUTD, s4.y);
  atomicAdd(c + 18 * OUTD, s4.z); atomicAdd(c + 19 * OUTD, s4.w);
  atomicAdd(c + 20 * OUTD, s5.x); atomicAdd(c + 21 * OUTD, s5.y);
  atomicAdd(c + 22 * OUTD, s5.z); atomicAdd(c + 23 * OUTD, s5.w);
  atomicAdd(c + 24 * OUTD, s6.x); atomicAdd(c + 25 * OUTD, s6.y);
  atomicAdd(c + 26 * OUTD, s6.z); atomicAdd(c + 27 * OUTD, s6.w);
  atomicAdd(c + 28 * OUTD, s7.x); atomicAdd(c + 29 * OUTD, s7.y);
  atomicAdd(c + 30 * OUTD, s7.z); atomicAdd(c + 31 * OUTD, s7.w);
  atomicAdd(outsum + o, osum);
}

// ---------------------------------------------------------------------------
// K4: w1_new[h,i] = (w1[h,i] + dw1T[i,h]) / ||row h||_2
// dw1T[i,h] = B*c1[i,h,3] + c1[i,h,0]*corr1[i,h] + c1[i,h,1]*xsum[i]
//           + c1[i,h,2]*actsum[h];  c1 row index = i*32+h
// ---------------------------------------------------------------------------
__global__ __launch_bounds__(256) void k_w1(
    const float* __restrict__ w1, const float* __restrict__ heb,
    const float* __restrict__ corr1, const float* __restrict__ xsum,
    const float* __restrict__ actsum, float* __restrict__ w1out) {
  const int h = blockIdx.x;
  const int tid = threadIdx.x;
  const float ash = actsum[h];
  const float4* heb4 = (const float4*)heb;

  float val[8];
  float ss = 0.f;
#pragma unroll
  for (int r = 0; r < 8; ++r) {
    const int i = tid + 256 * r;
    float4 c = heb4[(size_t)i * HID + h];
    float v = w1[(size_t)h * IND + i] + 16384.0f * c.w +
              c.x * corr1[(size_t)i * HID + h] + c.y * xsum[i] + c.z * ash;
    val[r] = v;
    ss += v * v;
  }

  __shared__ float red[256];
  red[tid] = ss;
  __syncthreads();
  for (int s = 128; s > 0; s >>= 1) {
    if (tid < s) red[tid] += red[tid + s];
    __syncthreads();
  }
  const float inv = 1.0f / sqrtf(red[0]);
#pragma unroll
  for (int r = 0; r < 8; ++r) {
    const int i = tid + 256 * r;
    w1out[(size_t)h * IND + i] = val[r] * inv;
  }
}

// ---------------------------------------------------------------------------
// K5: w2_new[o,h] = (w2[o,h] + dw2T[h,o]) / ||row o||_2
// dw2T[h,o] = B*c2[h,o,3] + c2[h,o,0]*corr2[h,o] + c2[h,o,1]*actsum[h]
//           + c2[h,o,2]*outsum[o];  c2 row index = 65536 + h*512 + o
// ---------------------------------------------------------------------------
__global__ __launch_bounds__(256) void k_w2(
    const float* __restrict__ w2, const float* __restrict__ heb,
    const float* __restrict__ corr2, const float* __restrict__ actsum,
    const float* __restrict__ outsum, float* __restrict__ w2out) {
  const int o = blockIdx.x * 256 + threadIdx.x;
  const float oso = outsum[o];
  const float4* heb4 = (const float4*)heb;

  float val[HID];
  float ss = 0.f;
#pragma unroll
  for (int h = 0; h < HID; ++h) {
    float4 c = heb4[(size_t)(HID * IND) + (size_t)h * OUTD + o];
    float v = w2[(size_t)o * HID + h] + 16384.0f * c.w +
              c.x * corr2[(size_t)h * OUTD + o] + c.y * actsum[h] + c.z * oso;
    val[h] = v;
    ss += v * v;
  }
  const float inv = 1.0f / sqrtf(ss);
#pragma unroll
  for (int h = 0; h < HID; ++h) w2out[(size_t)o * HID + h] = val[h] * inv;
}

// ---------------------------------------------------------------------------
extern "C" void kernel_launch(void* const* d_in, const int* in_sizes, int n_in,
                              void* d_out, int out_size, void* d_ws,
                              size_t ws_size, hipStream_t stream) {
  const float* x   = (const float*)d_in[0];   // [16384, 2048]
  const float* w1  = (const float*)d_in[1];   // [32, 2048]
  const float* w2  = (const float*)d_in[2];   // [512, 32]
  const float* heb = (const float*)d_in[3];   // [81920, 4]

  float* out = (float*)d_out;                 // [16384, 512]
  float* w1o = out + (size_t)BATCH * OUTD;    // [32, 2048]
  float* w2o = w1o + (size_t)HID * IND;       // [512, 32]

  float* ws     = (float*)d_ws;
  float* act    = ws;                                  // 16384*32 = 524288
  float* corr1  = act + (size_t)BATCH * HID;           // 2048*32  = 65536
  float* corr2  = corr1 + (size_t)IND * HID;           // 32*512   = 16384
  float* xsum   = corr2 + (size_t)HID * OUTD;          // 2048
  float* actsum = xsum + IND;                          // 32
  float* outsum = actsum + HID;                        // 512

  const int n4 = ZERO_ELEMS / 4;  // 21128 float4s
  k_zero <<<(n4 + 255) / 256, 256, 0, stream>>>((float4*)corr1, n4);

  k_act  <<<512, 256, 0, stream>>>(x, w1, act, actsum);
  k_corr1<<<512, 256, 0, stream>>>(x, act, corr1, xsum);
  k_fwd2 <<<512, 256, 0, stream>>>(act, w2, out, corr2, outsum);
  k_w1   <<<32, 256, 0, stream>>>(w1, heb, corr1, xsum, actsum, w1o);
  k_w2   <<<2, 256, 0, stream>>>(w2, heb, corr2, actsum, outsum, w2o);
}

// Round 4
// 359.752 us; speedup vs baseline: 2.0770x; 2.0514x over previous
//
#include <hip/hip_runtime.h>
#include <math.h>

// Problem constants
constexpr int BATCH = 16384;
constexpr int IND   = 2048;   // INPUT
constexpr int HID   = 32;     // HIDDEN
constexpr int OUTD  = 512;    // OUTPUT

constexpr int C1 = 64;    // b-chunks for corr1 (256 b each)
constexpr int C2 = 128;   // b-chunks for corr2 (128 b each)

// FMA helpers on named float4s (no arrays -> no scratch)
#define UPD4(C, A, S)                 \
  (C).x = fmaf((S), (A).x, (C).x);    \
  (C).y = fmaf((S), (A).y, (C).y);    \
  (C).z = fmaf((S), (A).z, (C).z);    \
  (C).w = fmaf((S), (A).w, (C).w);

#define DOT4(Z, A, W)                 \
  (Z) = fmaf((A).x, (W).x, (Z));      \
  (Z) = fmaf((A).y, (W).y, (Z));      \
  (Z) = fmaf((A).z, (W).z, (Z));      \
  (Z) = fmaf((A).w, (W).w, (Z));

// ---------------------------------------------------------------------------
// K0: zero actsum only (the sole surviving atomic target). Everything else
// is plain-stored with full coverage every call.
// ---------------------------------------------------------------------------
__global__ void k_zero32(float* __restrict__ p) { p[threadIdx.x] = 0.f; }

// ---------------------------------------------------------------------------
// K1: act[b,h] = relu(sum_k x[b,k]*w1[h,k]);  actsum via block-reduced atomics
// (16K low-contention adds). 512 blocks x 256 thr; thread = (h, 4 b-rows).
// ---------------------------------------------------------------------------
__global__ __launch_bounds__(256, 2) void k_act(
    const float* __restrict__ x, const float* __restrict__ w1,
    float* __restrict__ act, float* __restrict__ actsum) {
  const int tid = threadIdx.x;
  const int h = tid & 31;
  const int g = tid >> 5;                  // 0..7
  const int b0 = blockIdx.x * 32 + g * 4;  // 4 rows per thread

  const float4* __restrict__ w1p = (const float4*)(w1 + (size_t)h * IND);
  const float4* __restrict__ xp  = (const float4*)x;

  float acc0 = 0.f, acc1 = 0.f, acc2 = 0.f, acc3 = 0.f;
#pragma unroll 4
  for (int k4 = 0; k4 < IND / 4; ++k4) {
    float4 w  = w1p[k4];
    float4 x0 = xp[(size_t)(b0 + 0) * (IND / 4) + k4];
    float4 x1 = xp[(size_t)(b0 + 1) * (IND / 4) + k4];
    float4 x2 = xp[(size_t)(b0 + 2) * (IND / 4) + k4];
    float4 x3 = xp[(size_t)(b0 + 3) * (IND / 4) + k4];
    DOT4(acc0, x0, w);
    DOT4(acc1, x1, w);
    DOT4(acc2, x2, w);
    DOT4(acc3, x3, w);
  }

  float a0 = acc0 > 0.f ? acc0 : 0.f;
  float a1 = acc1 > 0.f ? acc1 : 0.f;
  float a2 = acc2 > 0.f ? acc2 : 0.f;
  float a3 = acc3 > 0.f ? acc3 : 0.f;
  act[(size_t)(b0 + 0) * HID + h] = a0;
  act[(size_t)(b0 + 1) * HID + h] = a1;
  act[(size_t)(b0 + 2) * HID + h] = a2;
  act[(size_t)(b0 + 3) * HID + h] = a3;

  __shared__ float red[256];
  red[tid] = a0 + a1 + a2 + a3;
  __syncthreads();
  if (tid < 32) {
    float s = 0.f;
#pragma unroll
    for (int gg = 0; gg < 8; ++gg) s += red[tid + 32 * gg];
    atomicAdd(actsum + tid, s);
  }
}

// ---------------------------------------------------------------------------
// K2: privatized corr1 partials — NO atomics (round-3 was atomic-bound:
// 2048 serialized RMWs per 64B line => 471 us @ 4.5% VALU).
// grid = 4 i-tiles x 64 b-chunks(256 b) = 256 blocks.
// thread owns i = i0+2*tid (+1), all 32 j in 16 named float4 accs.
// Writes corr1_part[chunk][i][j] + xsum_part[chunk][i] with plain stores.
// ---------------------------------------------------------------------------
__global__ __launch_bounds__(256, 2) void k_corr1p(
    const float* __restrict__ x, const float* __restrict__ act,
    float* __restrict__ corr1_part, float* __restrict__ xsum_part) {
  const int tid = threadIdx.x;
  const int i0 = (blockIdx.x & 3) * 512;
  const int chunk = blockIdx.x >> 2;
  const int b0 = chunk * 256;

  __shared__ float act_s[256][HID];
  {
    const float4* ag = (const float4*)(act + (size_t)b0 * HID);
    float4* as = (float4*)(&act_s[0][0]);
#pragma unroll
    for (int q = 0; q < 8; ++q) as[tid + 256 * q] = ag[tid + 256 * q];
  }
  __syncthreads();

  const float2* __restrict__ xp = (const float2*)x;
  const int i2 = i0 / 2 + tid;

  float4 c00{0,0,0,0}, c01{0,0,0,0}, c02{0,0,0,0}, c03{0,0,0,0};
  float4 c04{0,0,0,0}, c05{0,0,0,0}, c06{0,0,0,0}, c07{0,0,0,0};
  float4 c10{0,0,0,0}, c11{0,0,0,0}, c12{0,0,0,0}, c13{0,0,0,0};
  float4 c14{0,0,0,0}, c15{0,0,0,0}, c16{0,0,0,0}, c17{0,0,0,0};
  float xs0 = 0.f, xs1 = 0.f;

#pragma unroll 2
  for (int b = 0; b < 256; ++b) {
    float2 xv = xp[(size_t)(b0 + b) * (IND / 2) + i2];
    xs0 += xv.x; xs1 += xv.y;
    const float4* ar = (const float4*)(&act_s[b][0]);
    float4 a0 = ar[0], a1 = ar[1], a2 = ar[2], a3 = ar[3];
    float4 a4 = ar[4], a5 = ar[5], a6 = ar[6], a7 = ar[7];
    UPD4(c00, a0, xv.x); UPD4(c01, a1, xv.x); UPD4(c02, a2, xv.x); UPD4(c03, a3, xv.x);
    UPD4(c04, a4, xv.x); UPD4(c05, a5, xv.x); UPD4(c06, a6, xv.x); UPD4(c07, a7, xv.x);
    UPD4(c10, a0, xv.y); UPD4(c11, a1, xv.y); UPD4(c12, a2, xv.y); UPD4(c13, a3, xv.y);
    UPD4(c14, a4, xv.y); UPD4(c15, a5, xv.y); UPD4(c16, a6, xv.y); UPD4(c17, a7, xv.y);
  }

  const int ia = i0 + 2 * tid;
  float4* p0 = (float4*)(corr1_part + (size_t)chunk * (IND * HID) + (size_t)ia * HID);
  float4* p1 = (float4*)(corr1_part + (size_t)chunk * (IND * HID) + (size_t)(ia + 1) * HID);
  p0[0] = c00; p0[1] = c01; p0[2] = c02; p0[3] = c03;
  p0[4] = c04; p0[5] = c05; p0[6] = c06; p0[7] = c07;
  p1[0] = c10; p1[1] = c11; p1[2] = c12; p1[3] = c13;
  p1[4] = c14; p1[5] = c15; p1[6] = c16; p1[7] = c17;
  xsum_part[(size_t)chunk * IND + ia] = xs0;
  xsum_part[(size_t)chunk * IND + ia + 1] = xs1;
}

// ---------------------------------------------------------------------------
// K2b: deterministic reduce of corr1/xsum partials. grid = 256 x 256.
// ---------------------------------------------------------------------------
__global__ __launch_bounds__(256) void k_red1(
    const float* __restrict__ corr1_part, const float* __restrict__ xsum_part,
    float* __restrict__ corr1, float* __restrict__ xsum) {
  const int e = blockIdx.x * 256 + threadIdx.x;  // < 65536
  float s = 0.f;
#pragma unroll 8
  for (int c = 0; c < C1; ++c) s += corr1_part[(size_t)c * (IND * HID) + e];
  corr1[e] = s;
  if (e < IND) {
    float t = 0.f;
#pragma unroll 8
    for (int c = 0; c < C1; ++c) t += xsum_part[(size_t)c * IND + e];
    xsum[e] = t;
  }
}

// ---------------------------------------------------------------------------
// K3: forward layer 2 + privatized corr2/outsum partials — NO atomics.
// grid = 2 o-tiles x 128 b-chunks(128 b) = 256 blocks; thread owns one o.
// ---------------------------------------------------------------------------
__global__ __launch_bounds__(256, 2) void k_fwd2p(
    const float* __restrict__ act, const float* __restrict__ w2,
    float* __restrict__ out, float* __restrict__ corr2_part,
    float* __restrict__ outsum_part) {
  const int tid = threadIdx.x;
  const int o = (blockIdx.x & 1) * 256 + tid;
  const int chunk = blockIdx.x >> 1;
  const int b0 = chunk * 128;

  __shared__ float act_s[128][HID];
  {
    const float4* ag = (const float4*)(act + (size_t)b0 * HID);
    float4* as = (float4*)(&act_s[0][0]);
#pragma unroll
    for (int q = 0; q < 4; ++q) as[tid + 256 * q] = ag[tid + 256 * q];
  }

  const float4* w2p = (const float4*)(w2 + (size_t)o * HID);
  float4 w0 = w2p[0], w1r = w2p[1], w2r_ = w2p[2], w3 = w2p[3];
  float4 w4 = w2p[4], w5 = w2p[5], w6 = w2p[6], w7 = w2p[7];

  float4 s0{0,0,0,0}, s1{0,0,0,0}, s2{0,0,0,0}, s3{0,0,0,0};
  float4 s4{0,0,0,0}, s5{0,0,0,0}, s6{0,0,0,0}, s7{0,0,0,0};
  float osum = 0.f;

  __syncthreads();
  for (int b = 0; b < 128; ++b) {
    const float4* ar = (const float4*)(&act_s[b][0]);
    float4 a0 = ar[0], a1 = ar[1], a2 = ar[2], a3 = ar[3];
    float4 a4 = ar[4], a5 = ar[5], a6 = ar[6], a7 = ar[7];
    float z = 0.f;
    DOT4(z, a0, w0); DOT4(z, a1, w1r); DOT4(z, a2, w2r_); DOT4(z, a3, w3);
    DOT4(z, a4, w4); DOT4(z, a5, w5);  DOT4(z, a6, w6);   DOT4(z, a7, w7);
    float ov = 1.0f / (1.0f + __expf(-z)) - 0.4f;
    out[(size_t)(b0 + b) * OUTD + o] = ov;
    osum += ov;
    UPD4(s0, a0, ov); UPD4(s1, a1, ov); UPD4(s2, a2, ov); UPD4(s3, a3, ov);
    UPD4(s4, a4, ov); UPD4(s5, a5, ov); UPD4(s6, a6, ov); UPD4(s7, a7, ov);
  }

  // corr2_part[chunk][h][o]: 32 coalesced stores, stride OUTD
  float* c = corr2_part + (size_t)chunk * (HID * OUTD) + o;
  c[0 * OUTD]  = s0.x; c[1 * OUTD]  = s0.y; c[2 * OUTD]  = s0.z; c[3 * OUTD]  = s0.w;
  c[4 * OUTD]  = s1.x; c[5 * OUTD]  = s1.y; c[6 * OUTD]  = s1.z; c[7 * OUTD]  = s1.w;
  c[8 * OUTD]  = s2.x; c[9 * OUTD]  = s2.y; c[10 * OUTD] = s2.z; c[11 * OUTD] = s2.w;
  c[12 * OUTD] = s3.x; c[13 * OUTD] = s3.y; c[14 * OUTD] = s3.z; c[15 * OUTD] = s3.w;
  c[16 * OUTD] = s4.x; c[17 * OUTD] = s4.y; c[18 * OUTD] = s4.z; c[19 * OUTD] = s4.w;
  c[20 * OUTD] = s5.x; c[21 * OUTD] = s5.y; c[22 * OUTD] = s5.z; c[23 * OUTD] = s5.w;
  c[24 * OUTD] = s6.x; c[25 * OUTD] = s6.y; c[26 * OUTD] = s6.z; c[27 * OUTD] = s6.w;
  c[28 * OUTD] = s7.x; c[29 * OUTD] = s7.y; c[30 * OUTD] = s7.z; c[31 * OUTD] = s7.w;
  outsum_part[(size_t)chunk * OUTD + o] = osum;
}

// ---------------------------------------------------------------------------
// K3b: deterministic reduce of corr2/outsum partials. grid = 64 x 256.
// ---------------------------------------------------------------------------
__global__ __launch_bounds__(256) void k_red2(
    const float* __restrict__ corr2_part, const float* __restrict__ outsum_part,
    float* __restrict__ corr2, float* __restrict__ outsum) {
  const int e = blockIdx.x * 256 + threadIdx.x;  // < 16384
  float s = 0.f;
#pragma unroll 8
  for (int c = 0; c < C2; ++c) s += corr2_part[(size_t)c * (HID * OUTD) + e];
  corr2[e] = s;
  if (e < OUTD) {
    float t = 0.f;
#pragma unroll 8
    for (int c = 0; c < C2; ++c) t += outsum_part[(size_t)c * OUTD + e];
    outsum[e] = t;
  }
}

// ---------------------------------------------------------------------------
// K4: w1_new[h,i] = (w1[h,i] + dw1T[i,h]) / ||row h||_2
// ---------------------------------------------------------------------------
__global__ __launch_bounds__(256) void k_w1(
    const float* __restrict__ w1, const float* __restrict__ heb,
    const float* __restrict__ corr1, const float* __restrict__ xsum,
    const float* __restrict__ actsum, float* __restrict__ w1out) {
  const int h = blockIdx.x;
  const int tid = threadIdx.x;
  const float ash = actsum[h];
  const float4* heb4 = (const float4*)heb;

  float val[8];
  float ss = 0.f;
#pragma unroll
  for (int r = 0; r < 8; ++r) {
    const int i = tid + 256 * r;
    float4 c = heb4[(size_t)i * HID + h];
    float v = w1[(size_t)h * IND + i] + 16384.0f * c.w +
              c.x * corr1[(size_t)i * HID + h] + c.y * xsum[i] + c.z * ash;
    val[r] = v;
    ss += v * v;
  }

  __shared__ float red[256];
  red[tid] = ss;
  __syncthreads();
  for (int s = 128; s > 0; s >>= 1) {
    if (tid < s) red[tid] += red[tid + s];
    __syncthreads();
  }
  const float inv = 1.0f / sqrtf(red[0]);
#pragma unroll
  for (int r = 0; r < 8; ++r) {
    const int i = tid + 256 * r;
    w1out[(size_t)h * IND + i] = val[r] * inv;
  }
}

// ---------------------------------------------------------------------------
// K5: w2_new[o,h] = (w2[o,h] + dw2T[h,o]) / ||row o||_2
// ---------------------------------------------------------------------------
__global__ __launch_bounds__(256) void k_w2(
    const float* __restrict__ w2, const float* __restrict__ heb,
    const float* __restrict__ corr2, const float* __restrict__ actsum,
    const float* __restrict__ outsum, float* __restrict__ w2out) {
  const int o = blockIdx.x * 256 + threadIdx.x;
  const float oso = outsum[o];
  const float4* heb4 = (const float4*)heb;

  float val[HID];
  float ss = 0.f;
#pragma unroll
  for (int h = 0; h < HID; ++h) {
    float4 c = heb4[(size_t)(HID * IND) + (size_t)h * OUTD + o];
    float v = w2[(size_t)o * HID + h] + 16384.0f * c.w +
              c.x * corr2[(size_t)h * OUTD + o] + c.y * actsum[h] + c.z * oso;
    val[h] = v;
    ss += v * v;
  }
  const float inv = 1.0f / sqrtf(ss);
#pragma unroll
  for (int h = 0; h < HID; ++h) w2out[(size_t)o * HID + h] = val[h] * inv;
}

// ---------------------------------------------------------------------------
extern "C" void kernel_launch(void* const* d_in, const int* in_sizes, int n_in,
                              void* d_out, int out_size, void* d_ws,
                              size_t ws_size, hipStream_t stream) {
  const float* x   = (const float*)d_in[0];   // [16384, 2048]
  const float* w1  = (const float*)d_in[1];   // [32, 2048]
  const float* w2  = (const float*)d_in[2];   // [512, 32]
  const float* heb = (const float*)d_in[3];   // [81920, 4]

  float* out = (float*)d_out;                 // [16384, 512]
  float* w1o = out + (size_t)BATCH * OUTD;    // [32, 2048]
  float* w2o = w1o + (size_t)HID * IND;       // [512, 32]

  float* ws = (float*)d_ws;
  float* act         = ws;                                     // 524288
  float* corr1       = act + (size_t)BATCH * HID;              // 65536
  float* corr2       = corr1 + (size_t)IND * HID;              // 16384
  float* xsum        = corr2 + (size_t)HID * OUTD;             // 2048
  float* actsum      = xsum + IND;                             // 32
  float* outsum      = actsum + HID;                           // 512
  float* corr1_part  = outsum + OUTD;                          // 64*65536 = 4194304
  float* xsum_part   = corr1_part + (size_t)C1 * IND * HID;    // 64*2048 = 131072
  float* corr2_part  = xsum_part + (size_t)C1 * IND;           // 128*16384 = 2097152
  float* outsum_part = corr2_part + (size_t)C2 * HID * OUTD;   // 128*512 = 65536
  // total ws use ≈ 7.07M floats ≈ 28.3 MB

  k_zero32<<<1, 32, 0, stream>>>(actsum);
  k_act   <<<512, 256, 0, stream>>>(x, w1, act, actsum);
  k_corr1p<<<256, 256, 0, stream>>>(x, act, corr1_part, xsum_part);
  k_red1  <<<256, 256, 0, stream>>>(corr1_part, xsum_part, corr1, xsum);
  k_fwd2p <<<256, 256, 0, stream>>>(act, w2, out, corr2_part, outsum_part);
  k_red2  <<<64, 256, 0, stream>>>(corr2_part, outsum_part, corr2, outsum);
  k_w1    <<<32, 256, 0, stream>>>(w1, heb, corr1, xsum, actsum, w1o);
  k_w2    <<<2, 256, 0, stream>>>(w2, heb, corr2, actsum, outsum, w2o);
}

// Round 7
// 205.853 us; speedup vs baseline: 3.6298x; 1.7476x over previous
//
#include <hip/hip_runtime.h>
#include <math.h>

// Problem constants
constexpr int BATCH = 16384;
constexpr int IND   = 2048;   // INPUT
constexpr int HID   = 32;     // HIDDEN
constexpr int OUTD  = 512;    // OUTPUT

constexpr int C1 = 64;    // b-chunks for corr1 (256 b each)
constexpr int C2 = 128;   // b-chunks for corr2 (128 b each)
constexpr int AC = 256;   // k_act_t blocks (actsum chunks)

// FMA helpers on named float4s (no arrays -> no scratch)
#define UPD4(C, A, S)                 \
  (C).x = fmaf((S), (A).x, (C).x);    \
  (C).y = fmaf((S), (A).y, (C).y);    \
  (C).z = fmaf((S), (A).z, (C).z);    \
  (C).w = fmaf((S), (A).w, (C).w);

#define DOT4(Z, A, W)                 \
  (Z) = fmaf((A).x, (W).x, (Z));      \
  (Z) = fmaf((A).y, (W).y, (Z));      \
  (Z) = fmaf((A).z, (W).z, (Z));      \
  (Z) = fmaf((A).w, (W).w, (Z));

// ---------------------------------------------------------------------------
// K1: tiled layer-1 GEMM. act[b,h] = relu(sum_k x[b,k]*w1[h,k]).
// Round-4 version was a 32-line w1 gather per wave instr (VALU 16%, 256 us).
// Now: x tile [64][132] + w1T chunk [128][36] in LDS, all reads broadcast-
// class or 2-way aliased. Thread = (2 rows, 4 h). No atomics: actsum goes
// to per-block partials (reduced in k_red1).
// grid = 256 blocks x 256 threads; block owns rows [blk*64, blk*64+64).
// ---------------------------------------------------------------------------
__global__ __launch_bounds__(256, 2) void k_act_t(
    const float* __restrict__ x, const float* __restrict__ w1,
    float* __restrict__ act, float* __restrict__ actsum_part) {
  const int tid = threadIdx.x;
  const int blk = blockIdx.x;           // 0..255
  const int b0 = blk * 64;

  __shared__ float xs[64 * 132];        // row stride 132 floats (16B-aligned)
  __shared__ float ws[128 * 36];        // [k][h], stride 36 (16B-aligned)
  __shared__ float asr[256 * 4];        // actsum reduction scratch

  const int rg = tid >> 3;              // 0..31 -> rows 2rg, 2rg+1
  const int h0 = (tid & 7) * 4;         // 0,4,...,28

  float4 acc0{0, 0, 0, 0}, acc1{0, 0, 0, 0};

  for (int kc = 0; kc < 16; ++kc) {
    const int k0 = kc * 128;
    __syncthreads();  // previous-iter LDS reads done before overwrite

    // load x tile: 64 rows x 128 k = 2048 float4, 8 per thread, coalesced
#pragma unroll
    for (int q = 0; q < 8; ++q) {
      const int m = tid + 256 * q;      // float4 index in tile
      const int r = m >> 5, c4 = m & 31;
      float4 v = *(const float4*)(x + (size_t)(b0 + r) * IND + k0 + 4 * c4);
      *(float4*)(&xs[r * 132 + 4 * c4]) = v;
    }
    // load w1 chunk transposed: ws[k][h]; thread: h = tid>>3, 16 k's
    {
      const int h = tid >> 3;           // 0..31
      const int kq = (tid & 7) * 16;
#pragma unroll
      for (int j = 0; j < 4; ++j) {
        float4 wv = *(const float4*)(w1 + (size_t)h * IND + k0 + kq + 4 * j);
        ws[(kq + 4 * j + 0) * 36 + h] = wv.x;
        ws[(kq + 4 * j + 1) * 36 + h] = wv.y;
        ws[(kq + 4 * j + 2) * 36 + h] = wv.z;
        ws[(kq + 4 * j + 3) * 36 + h] = wv.w;
      }
    }
    __syncthreads();

    // compute: kk in steps of 4 -> 6 ds_read_b128 per 32 FMA
#pragma unroll 4
    for (int kk = 0; kk < 128; kk += 4) {
      float4 xa = *(const float4*)(&xs[(2 * rg) * 132 + kk]);
      float4 xb = *(const float4*)(&xs[(2 * rg + 1) * 132 + kk]);
      float4 w0 = *(const float4*)(&ws[(kk + 0) * 36 + h0]);
      float4 w1v = *(const float4*)(&ws[(kk + 1) * 36 + h0]);
      float4 w2v = *(const float4*)(&ws[(kk + 2) * 36 + h0]);
      float4 w3v = *(const float4*)(&ws[(kk + 3) * 36 + h0]);
      UPD4(acc0, w0, xa.x); UPD4(acc0, w1v, xa.y);
      UPD4(acc0, w2v, xa.z); UPD4(acc0, w3v, xa.w);
      UPD4(acc1, w0, xb.x); UPD4(acc1, w1v, xb.y);
      UPD4(acc1, w2v, xb.z); UPD4(acc1, w3v, xb.w);
    }
  }

  // relu
  acc0.x = acc0.x > 0.f ? acc0.x : 0.f;  acc0.y = acc0.y > 0.f ? acc0.y : 0.f;
  acc0.z = acc0.z > 0.f ? acc0.z : 0.f;  acc0.w = acc0.w > 0.f ? acc0.w : 0.f;
  acc1.x = acc1.x > 0.f ? acc1.x : 0.f;  acc1.y = acc1.y > 0.f ? acc1.y : 0.f;
  acc1.z = acc1.z > 0.f ? acc1.z : 0.f;  acc1.w = acc1.w > 0.f ? acc1.w : 0.f;

  const int r0 = b0 + 2 * rg;
  *(float4*)(act + (size_t)r0 * HID + h0) = acc0;
  *(float4*)(act + (size_t)(r0 + 1) * HID + h0) = acc1;

  // actsum partial: per-thread (2-row) sums -> LDS -> 32-thread reduce
  asr[tid * 4 + 0] = acc0.x + acc1.x;
  asr[tid * 4 + 1] = acc0.y + acc1.y;
  asr[tid * 4 + 2] = acc0.z + acc1.z;
  asr[tid * 4 + 3] = acc0.w + acc1.w;
  __syncthreads();
  if (tid < 32) {
    const int hg = tid >> 2, j = tid & 3;  // h = hg*4 + j
    float s = 0.f;
#pragma unroll
    for (int rr = 0; rr < 32; ++rr) s += asr[(rr * 8 + hg) * 4 + j];
    actsum_part[blk * HID + hg * 4 + j] = s;
  }
}

// ---------------------------------------------------------------------------
// K2: privatized corr1 partials — NO atomics.
// grid = 4 i-tiles x 64 b-chunks(256 b) = 256 blocks.
// ---------------------------------------------------------------------------
__global__ __launch_bounds__(256, 2) void k_corr1p(
    const float* __restrict__ x, const float* __restrict__ act,
    float* __restrict__ corr1_part, float* __restrict__ xsum_part) {
  const int tid = threadIdx.x;
  const int i0 = (blockIdx.x & 3) * 512;
  const int chunk = blockIdx.x >> 2;
  const int b0 = chunk * 256;

  __shared__ float act_s[256][HID];
  {
    const float4* ag = (const float4*)(act + (size_t)b0 * HID);
    float4* as = (float4*)(&act_s[0][0]);
#pragma unroll
    for (int q = 0; q < 8; ++q) as[tid + 256 * q] = ag[tid + 256 * q];
  }
  __syncthreads();

  const float2* __restrict__ xp = (const float2*)x;
  const int i2 = i0 / 2 + tid;

  float4 c00{0,0,0,0}, c01{0,0,0,0}, c02{0,0,0,0}, c03{0,0,0,0};
  float4 c04{0,0,0,0}, c05{0,0,0,0}, c06{0,0,0,0}, c07{0,0,0,0};
  float4 c10{0,0,0,0}, c11{0,0,0,0}, c12{0,0,0,0}, c13{0,0,0,0};
  float4 c14{0,0,0,0}, c15{0,0,0,0}, c16{0,0,0,0}, c17{0,0,0,0};
  float xs0 = 0.f, xs1 = 0.f;

#pragma unroll 2
  for (int b = 0; b < 256; ++b) {
    float2 xv = xp[(size_t)(b0 + b) * (IND / 2) + i2];
    xs0 += xv.x; xs1 += xv.y;
    const float4* ar = (const float4*)(&act_s[b][0]);
    float4 a0 = ar[0], a1 = ar[1], a2 = ar[2], a3 = ar[3];
    float4 a4 = ar[4], a5 = ar[5], a6 = ar[6], a7 = ar[7];
    UPD4(c00, a0, xv.x); UPD4(c01, a1, xv.x); UPD4(c02, a2, xv.x); UPD4(c03, a3, xv.x);
    UPD4(c04, a4, xv.x); UPD4(c05, a5, xv.x); UPD4(c06, a6, xv.x); UPD4(c07, a7, xv.x);
    UPD4(c10, a0, xv.y); UPD4(c11, a1, xv.y); UPD4(c12, a2, xv.y); UPD4(c13, a3, xv.y);
    UPD4(c14, a4, xv.y); UPD4(c15, a5, xv.y); UPD4(c16, a6, xv.y); UPD4(c17, a7, xv.y);
  }

  const int ia = i0 + 2 * tid;
  float4* p0 = (float4*)(corr1_part + (size_t)chunk * (IND * HID) + (size_t)ia * HID);
  float4* p1 = (float4*)(corr1_part + (size_t)chunk * (IND * HID) + (size_t)(ia + 1) * HID);
  p0[0] = c00; p0[1] = c01; p0[2] = c02; p0[3] = c03;
  p0[4] = c04; p0[5] = c05; p0[6] = c06; p0[7] = c07;
  p1[0] = c10; p1[1] = c11; p1[2] = c12; p1[3] = c13;
  p1[4] = c14; p1[5] = c15; p1[6] = c16; p1[7] = c17;
  xsum_part[(size_t)chunk * IND + ia] = xs0;
  xsum_part[(size_t)chunk * IND + ia + 1] = xs1;
}

// ---------------------------------------------------------------------------
// K2b: deterministic reduce of corr1/xsum/actsum partials. grid = 256 x 256.
// ---------------------------------------------------------------------------
__global__ __launch_bounds__(256) void k_red1(
    const float* __restrict__ corr1_part, const float* __restrict__ xsum_part,
    const float* __restrict__ actsum_part,
    float* __restrict__ corr1, float* __restrict__ xsum,
    float* __restrict__ actsum) {
  const int e = blockIdx.x * 256 + threadIdx.x;  // < 65536
  float s = 0.f;
#pragma unroll 8
  for (int c = 0; c < C1; ++c) s += corr1_part[(size_t)c * (IND * HID) + e];
  corr1[e] = s;
  if (e < IND) {
    float t = 0.f;
#pragma unroll 8
    for (int c = 0; c < C1; ++c) t += xsum_part[(size_t)c * IND + e];
    xsum[e] = t;
  }
  if (e < HID) {
    float t = 0.f;
#pragma unroll 8
    for (int c = 0; c < AC; ++c) t += actsum_part[(size_t)c * HID + e];
    actsum[e] = t;
  }
}

// ---------------------------------------------------------------------------
// K3: forward layer 2 + privatized corr2/outsum partials — NO atomics.
// grid = 2 o-tiles x 128 b-chunks(128 b) = 256 blocks; thread owns one o.
// ---------------------------------------------------------------------------
__global__ __launch_bounds__(256, 2) void k_fwd2p(
    const float* __restrict__ act, const float* __restrict__ w2,
    float* __restrict__ out, float* __restrict__ corr2_part,
    float* __restrict__ outsum_part) {
  const int tid = threadIdx.x;
  const int o = (blockIdx.x & 1) * 256 + tid;
  const int chunk = blockIdx.x >> 1;
  const int b0 = chunk * 128;

  __shared__ float act_s[128][HID];
  {
    const float4* ag = (const float4*)(act + (size_t)b0 * HID);
    float4* as = (float4*)(&act_s[0][0]);
#pragma unroll
    for (int q = 0; q < 4; ++q) as[tid + 256 * q] = ag[tid + 256 * q];
  }

  const float4* w2p = (const float4*)(w2 + (size_t)o * HID);
  float4 w0 = w2p[0], w1r = w2p[1], w2r_ = w2p[2], w3 = w2p[3];
  float4 w4 = w2p[4], w5 = w2p[5], w6 = w2p[6], w7 = w2p[7];

  float4 s0{0,0,0,0}, s1{0,0,0,0}, s2{0,0,0,0}, s3{0,0,0,0};
  float4 s4{0,0,0,0}, s5{0,0,0,0}, s6{0,0,0,0}, s7{0,0,0,0};
  float osum = 0.f;

  __syncthreads();
  for (int b = 0; b < 128; ++b) {
    const float4* ar = (const float4*)(&act_s[b][0]);
    float4 a0 = ar[0], a1 = ar[1], a2 = ar[2], a3 = ar[3];
    float4 a4 = ar[4], a5 = ar[5], a6 = ar[6], a7 = ar[7];
    float z = 0.f;
    DOT4(z, a0, w0); DOT4(z, a1, w1r); DOT4(z, a2, w2r_); DOT4(z, a3, w3);
    DOT4(z, a4, w4); DOT4(z, a5, w5);  DOT4(z, a6, w6);   DOT4(z, a7, w7);
    float ov = 1.0f / (1.0f + __expf(-z)) - 0.4f;
    out[(size_t)(b0 + b) * OUTD + o] = ov;
    osum += ov;
    UPD4(s0, a0, ov); UPD4(s1, a1, ov); UPD4(s2, a2, ov); UPD4(s3, a3, ov);
    UPD4(s4, a4, ov); UPD4(s5, a5, ov); UPD4(s6, a6, ov); UPD4(s7, a7, ov);
  }

  float* c = corr2_part + (size_t)chunk * (HID * OUTD) + o;
  c[0 * OUTD]  = s0.x; c[1 * OUTD]  = s0.y; c[2 * OUTD]  = s0.z; c[3 * OUTD]  = s0.w;
  c[4 * OUTD]  = s1.x; c[5 * OUTD]  = s1.y; c[6 * OUTD]  = s1.z; c[7 * OUTD]  = s1.w;
  c[8 * OUTD]  = s2.x; c[9 * OUTD]  = s2.y; c[10 * OUTD] = s2.z; c[11 * OUTD] = s2.w;
  c[12 * OUTD] = s3.x; c[13 * OUTD] = s3.y; c[14 * OUTD] = s3.z; c[15 * OUTD] = s3.w;
  c[16 * OUTD] = s4.x; c[17 * OUTD] = s4.y; c[18 * OUTD] = s4.z; c[19 * OUTD] = s4.w;
  c[20 * OUTD] = s5.x; c[21 * OUTD] = s5.y; c[22 * OUTD] = s5.z; c[23 * OUTD] = s5.w;
  c[24 * OUTD] = s6.x; c[25 * OUTD] = s6.y; c[26 * OUTD] = s6.z; c[27 * OUTD] = s6.w;
  c[28 * OUTD] = s7.x; c[29 * OUTD] = s7.y; c[30 * OUTD] = s7.z; c[31 * OUTD] = s7.w;
  outsum_part[(size_t)chunk * OUTD + o] = osum;
}

// ---------------------------------------------------------------------------
// K3b: deterministic reduce of corr2/outsum partials. grid = 64 x 256.
// ---------------------------------------------------------------------------
__global__ __launch_bounds__(256) void k_red2(
    const float* __restrict__ corr2_part, const float* __restrict__ outsum_part,
    float* __restrict__ corr2, float* __restrict__ outsum) {
  const int e = blockIdx.x * 256 + threadIdx.x;  // < 16384
  float s = 0.f;
#pragma unroll 8
  for (int c = 0; c < C2; ++c) s += corr2_part[(size_t)c * (HID * OUTD) + e];
  corr2[e] = s;
  if (e < OUTD) {
    float t = 0.f;
#pragma unroll 8
    for (int c = 0; c < C2; ++c) t += outsum_part[(size_t)c * OUTD + e];
    outsum[e] = t;
  }
}

// ---------------------------------------------------------------------------
// K4: w1_new[h,i] = (w1[h,i] + dw1T[i,h]) / ||row h||_2
// ---------------------------------------------------------------------------
__global__ __launch_bounds__(256) void k_w1(
    const float* __restrict__ w1, const float* __restrict__ heb,
    const float* __restrict__ corr1, const float* __restrict__ xsum,
    const float* __restrict__ actsum, float* __restrict__ w1out) {
  const int h = blockIdx.x;
  const int tid = threadIdx.x;
  const float ash = actsum[h];
  const float4* heb4 = (const float4*)heb;

  float val[8];
  float ss = 0.f;
#pragma unroll
  for (int r = 0; r < 8; ++r) {
    const int i = tid + 256 * r;
    float4 c = heb4[(size_t)i * HID + h];
    float v = w1[(size_t)h * IND + i] + 16384.0f * c.w +
              c.x * corr1[(size_t)i * HID + h] + c.y * xsum[i] + c.z * ash;
    val[r] = v;
    ss += v * v;
  }

  __shared__ float red[256];
  red[tid] = ss;
  __syncthreads();
  for (int s = 128; s > 0; s >>= 1) {
    if (tid < s) red[tid] += red[tid + s];
    __syncthreads();
  }
  const float inv = 1.0f / sqrtf(red[0]);
#pragma unroll
  for (int r = 0; r < 8; ++r) {
    const int i = tid + 256 * r;
    w1out[(size_t)h * IND + i] = val[r] * inv;
  }
}

// ---------------------------------------------------------------------------
// K5: w2_new[o,h] = (w2[o,h] + dw2T[h,o]) / ||row o||_2
// ---------------------------------------------------------------------------
__global__ __launch_bounds__(256) void k_w2(
    const float* __restrict__ w2, const float* __restrict__ heb,
    const float* __restrict__ corr2, const float* __restrict__ actsum,
    const float* __restrict__ outsum, float* __restrict__ w2out) {
  const int o = blockIdx.x * 256 + threadIdx.x;
  const float oso = outsum[o];
  const float4* heb4 = (const float4*)heb;

  float val[HID];
  float ss = 0.f;
#pragma unroll
  for (int h = 0; h < HID; ++h) {
    float4 c = heb4[(size_t)(HID * IND) + (size_t)h * OUTD + o];
    float v = w2[(size_t)o * HID + h] + 16384.0f * c.w +
              c.x * corr2[(size_t)h * OUTD + o] + c.y * actsum[h] + c.z * oso;
    val[h] = v;
    ss += v * v;
  }
  const float inv = 1.0f / sqrtf(ss);
#pragma unroll
  for (int h = 0; h < HID; ++h) w2out[(size_t)o * HID + h] = val[h] * inv;
}

// ---------------------------------------------------------------------------
extern "C" void kernel_launch(void* const* d_in, const int* in_sizes, int n_in,
                              void* d_out, int out_size, void* d_ws,
                              size_t ws_size, hipStream_t stream) {
  const float* x   = (const float*)d_in[0];   // [16384, 2048]
  const float* w1  = (const float*)d_in[1];   // [32, 2048]
  const float* w2  = (const float*)d_in[2];   // [512, 32]
  const float* heb = (const float*)d_in[3];   // [81920, 4]

  float* out = (float*)d_out;                 // [16384, 512]
  float* w1o = out + (size_t)BATCH * OUTD;    // [32, 2048]
  float* w2o = w1o + (size_t)HID * IND;       // [512, 32]

  float* ws = (float*)d_ws;
  float* act         = ws;                                     // 524288
  float* corr1       = act + (size_t)BATCH * HID;              // 65536
  float* corr2       = corr1 + (size_t)IND * HID;              // 16384
  float* xsum        = corr2 + (size_t)HID * OUTD;             // 2048
  float* actsum      = xsum + IND;                             // 32
  float* outsum      = actsum + HID;                           // 512
  float* corr1_part  = outsum + OUTD;                          // 64*65536
  float* xsum_part   = corr1_part + (size_t)C1 * IND * HID;    // 64*2048
  float* corr2_part  = xsum_part + (size_t)C1 * IND;           // 128*16384
  float* outsum_part = corr2_part + (size_t)C2 * HID * OUTD;   // 128*512
  float* actsum_part = outsum_part + (size_t)C2 * OUTD;        // 256*32
  // total ws use ≈ 7.08M floats ≈ 28.3 MB

  k_act_t <<<256, 256, 0, stream>>>(x, w1, act, actsum_part);
  k_corr1p<<<256, 256, 0, stream>>>(x, act, corr1_part, xsum_part);
  k_red1  <<<256, 256, 0, stream>>>(corr1_part, xsum_part, actsum_part,
                                    corr1, xsum, actsum);
  k_fwd2p <<<256, 256, 0, stream>>>(act, w2, out, corr2_part, outsum_part);
  k_red2  <<<64, 256, 0, stream>>>(corr2_part, outsum_part, corr2, outsum);
  k_w1    <<<32, 256, 0, stream>>>(w1, heb, corr1, xsum, actsum, w1o);
  k_w2    <<<2, 256, 0, stream>>>(w2, heb, corr2, actsum, outsum, w2o);
}

// Round 9
// 191.800 us; speedup vs baseline: 3.8958x; 1.0733x over previous
//
#include <hip/hip_runtime.h>
#include <math.h>

// Problem constants
constexpr int BATCH = 16384;
constexpr int IND   = 2048;   // INPUT
constexpr int HID   = 32;     // HIDDEN
constexpr int OUTD  = 512;    // OUTPUT

constexpr int C1 = 64;    // b-chunks for corr1 (256 b each)
constexpr int C2 = 128;   // b-chunks for corr2 (128 b each)
constexpr int AC = 512;   // k_act_c blocks (actsum chunks)

// FMA helpers on named float4s (no arrays -> no scratch)
#define UPD4(C, A, S)                 \
  (C).x = fmaf((S), (A).x, (C).x);    \
  (C).y = fmaf((S), (A).y, (C).y);    \
  (C).z = fmaf((S), (A).z, (C).z);    \
  (C).w = fmaf((S), (A).w, (C).w);

#define DOT4(Z, A, W)                 \
  (Z) = fmaf((A).x, (W).x, (Z));      \
  (Z) = fmaf((A).y, (W).y, (Z));      \
  (Z) = fmaf((A).z, (W).z, (Z));      \
  (Z) = fmaf((A).w, (W).w, (Z));

// ---------------------------------------------------------------------------
// K1: layer-1 GEMM, K-split x4 for occupancy (r7: grid 256 = 1 blk/CU, 10%
// occ, 79 us). grid = 1024 = (4 K-quarters) x (256 row-tiles of 64 rows).
// Thread = (2 rows, 4 h). x: broadcast-class global float4 (8 lanes share
// address). w1T chunk [128][36] in LDS only (18.4 KB -> 4 blk/CU).
// Transpose store lanes h=tid&31 -> banks (4k+h)%32 all-32, 2-way = free
// (r7 mapping was 8-way conflicted: 3.67M SQ_LDS_BANK_CONFLICT).
// Writes act_part[kq][b][h] partial sums (no relu yet).
// ---------------------------------------------------------------------------
__global__ __launch_bounds__(256, 4) void k_act_q(
    const float* __restrict__ x, const float* __restrict__ w1,
    float* __restrict__ act_part) {
  const int tid = threadIdx.x;
  const int kq = blockIdx.x >> 8;          // 0..3 K-quarter
  const int bt = blockIdx.x & 255;         // row tile
  const int b0 = bt * 64;
  const int kbase = kq * 512;

  __shared__ float ws[128 * 36];           // [k][h], stride 36

  const int rg = tid >> 3;                 // 0..31 -> rows 2rg, 2rg+1
  const int h0 = (tid & 7) * 4;            // 0,4,...,28
  const int r0 = b0 + 2 * rg;

  float4 acc0{0, 0, 0, 0}, acc1{0, 0, 0, 0};

  for (int kc = 0; kc < 4; ++kc) {
    const int k0 = kbase + kc * 128;
    __syncthreads();
    // load w1 chunk transposed: lane h = tid&31 covers all banks on store.
    {
      const int h = tid & 31;
      const int kk0 = (tid >> 5) * 16;     // 0,16,...,112
#pragma unroll
      for (int u = 0; u < 4; ++u) {
        float4 wv = *(const float4*)(w1 + (size_t)h * IND + k0 + kk0 + 4 * u);
        ws[(kk0 + 4 * u + 0) * 36 + h] = wv.x;
        ws[(kk0 + 4 * u + 1) * 36 + h] = wv.y;
        ws[(kk0 + 4 * u + 2) * 36 + h] = wv.z;
        ws[(kk0 + 4 * u + 3) * 36 + h] = wv.w;
      }
    }
    __syncthreads();

#pragma unroll 4
    for (int kk = 0; kk < 128; kk += 4) {
      float4 xa = *(const float4*)(x + (size_t)r0 * IND + k0 + kk);
      float4 xb = *(const float4*)(x + (size_t)(r0 + 1) * IND + k0 + kk);
      float4 w0 = *(const float4*)(&ws[(kk + 0) * 36 + h0]);
      float4 w1v = *(const float4*)(&ws[(kk + 1) * 36 + h0]);
      float4 w2v = *(const float4*)(&ws[(kk + 2) * 36 + h0]);
      float4 w3v = *(const float4*)(&ws[(kk + 3) * 36 + h0]);
      UPD4(acc0, w0, xa.x); UPD4(acc0, w1v, xa.y);
      UPD4(acc0, w2v, xa.z); UPD4(acc0, w3v, xa.w);
      UPD4(acc1, w0, xb.x); UPD4(acc1, w1v, xb.y);
      UPD4(acc1, w2v, xb.z); UPD4(acc1, w3v, xb.w);
    }
  }

  float* p = act_part + (size_t)kq * (BATCH * HID);
  *(float4*)(p + (size_t)r0 * HID + h0) = acc0;
  *(float4*)(p + (size_t)(r0 + 1) * HID + h0) = acc1;
}

// ---------------------------------------------------------------------------
// K1b: combine 4 K-quarter partials -> relu -> act; actsum block partials.
// grid = 512 x 256; thread owns one float4 of act (32 rows x 8 q per block).
// ---------------------------------------------------------------------------
__global__ __launch_bounds__(256) void k_act_c(
    const float* __restrict__ act_part, float* __restrict__ act,
    float* __restrict__ actsum_part) {
  const int tid = threadIdx.x;
  const int idx = blockIdx.x * 256 + tid;      // float4 index < 131072
  const float4* p0 = (const float4*)act_part;
  const float4* p1 = p0 + (BATCH * HID / 4);
  const float4* p2 = p1 + (BATCH * HID / 4);
  const float4* p3 = p2 + (BATCH * HID / 4);

  float4 a = p0[idx], b = p1[idx], c = p2[idx], d = p3[idx];
  float4 s;
  s.x = a.x + b.x + c.x + d.x;  s.y = a.y + b.y + c.y + d.y;
  s.z = a.z + b.z + c.z + d.z;  s.w = a.w + b.w + c.w + d.w;
  s.x = s.x > 0.f ? s.x : 0.f;  s.y = s.y > 0.f ? s.y : 0.f;
  s.z = s.z > 0.f ? s.z : 0.f;  s.w = s.w > 0.f ? s.w : 0.f;
  ((float4*)act)[idx] = s;

  __shared__ float asr[256 * 4];
  asr[tid * 4 + 0] = s.x; asr[tid * 4 + 1] = s.y;
  asr[tid * 4 + 2] = s.z; asr[tid * 4 + 3] = s.w;
  __syncthreads();
  if (tid < 32) {
    const int q = tid >> 2, j = tid & 3;       // h = q*4 + j
    float t = 0.f;
#pragma unroll
    for (int r = 0; r < 32; ++r) t += asr[(r * 8 + q) * 4 + j];
    actsum_part[blockIdx.x * HID + q * 4 + j] = t;
  }
}

// ---------------------------------------------------------------------------
// K2: privatized corr1 partials — NO atomics.
// grid = 4 i-tiles x 64 b-chunks(256 b) = 256 blocks.
// ---------------------------------------------------------------------------
__global__ __launch_bounds__(256, 2) void k_corr1p(
    const float* __restrict__ x, const float* __restrict__ act,
    float* __restrict__ corr1_part, float* __restrict__ xsum_part) {
  const int tid = threadIdx.x;
  const int i0 = (blockIdx.x & 3) * 512;
  const int chunk = blockIdx.x >> 2;
  const int b0 = chunk * 256;

  __shared__ float act_s[256][HID];
  {
    const float4* ag = (const float4*)(act + (size_t)b0 * HID);
    float4* as = (float4*)(&act_s[0][0]);
#pragma unroll
    for (int q = 0; q < 8; ++q) as[tid + 256 * q] = ag[tid + 256 * q];
  }
  __syncthreads();

  const float2* __restrict__ xp = (const float2*)x;
  const int i2 = i0 / 2 + tid;

  float4 c00{0,0,0,0}, c01{0,0,0,0}, c02{0,0,0,0}, c03{0,0,0,0};
  float4 c04{0,0,0,0}, c05{0,0,0,0}, c06{0,0,0,0}, c07{0,0,0,0};
  float4 c10{0,0,0,0}, c11{0,0,0,0}, c12{0,0,0,0}, c13{0,0,0,0};
  float4 c14{0,0,0,0}, c15{0,0,0,0}, c16{0,0,0,0}, c17{0,0,0,0};
  float xs0 = 0.f, xs1 = 0.f;

#pragma unroll 2
  for (int b = 0; b < 256; ++b) {
    float2 xv = xp[(size_t)(b0 + b) * (IND / 2) + i2];
    xs0 += xv.x; xs1 += xv.y;
    const float4* ar = (const float4*)(&act_s[b][0]);
    float4 a0 = ar[0], a1 = ar[1], a2 = ar[2], a3 = ar[3];
    float4 a4 = ar[4], a5 = ar[5], a6 = ar[6], a7 = ar[7];
    UPD4(c00, a0, xv.x); UPD4(c01, a1, xv.x); UPD4(c02, a2, xv.x); UPD4(c03, a3, xv.x);
    UPD4(c04, a4, xv.x); UPD4(c05, a5, xv.x); UPD4(c06, a6, xv.x); UPD4(c07, a7, xv.x);
    UPD4(c10, a0, xv.y); UPD4(c11, a1, xv.y); UPD4(c12, a2, xv.y); UPD4(c13, a3, xv.y);
    UPD4(c14, a4, xv.y); UPD4(c15, a5, xv.y); UPD4(c16, a6, xv.y); UPD4(c17, a7, xv.y);
  }

  const int ia = i0 + 2 * tid;
  float4* p0 = (float4*)(corr1_part + (size_t)chunk * (IND * HID) + (size_t)ia * HID);
  float4* p1 = (float4*)(corr1_part + (size_t)chunk * (IND * HID) + (size_t)(ia + 1) * HID);
  p0[0] = c00; p0[1] = c01; p0[2] = c02; p0[3] = c03;
  p0[4] = c04; p0[5] = c05; p0[6] = c06; p0[7] = c07;
  p1[0] = c10; p1[1] = c11; p1[2] = c12; p1[3] = c13;
  p1[4] = c14; p1[5] = c15; p1[6] = c16; p1[7] = c17;
  xsum_part[(size_t)chunk * IND + ia] = xs0;
  xsum_part[(size_t)chunk * IND + ia + 1] = xs1;
}

// ---------------------------------------------------------------------------
// K2b: deterministic reduce of corr1/xsum/actsum partials. grid = 256 x 256.
// ---------------------------------------------------------------------------
__global__ __launch_bounds__(256) void k_red1(
    const float* __restrict__ corr1_part, const float* __restrict__ xsum_part,
    const float* __restrict__ actsum_part,
    float* __restrict__ corr1, float* __restrict__ xsum,
    float* __restrict__ actsum) {
  const int e = blockIdx.x * 256 + threadIdx.x;  // < 65536
  float s = 0.f;
#pragma unroll 8
  for (int c = 0; c < C1; ++c) s += corr1_part[(size_t)c * (IND * HID) + e];
  corr1[e] = s;
  if (e < IND) {
    float t = 0.f;
#pragma unroll 8
    for (int c = 0; c < C1; ++c) t += xsum_part[(size_t)c * IND + e];
    xsum[e] = t;
  }
  if (e < HID) {
    float t = 0.f;
#pragma unroll 8
    for (int c = 0; c < AC; ++c) t += actsum_part[(size_t)c * HID + e];
    actsum[e] = t;
  }
}

// ---------------------------------------------------------------------------
// K3: forward layer 2 + privatized corr2/outsum partials — NO atomics.
// grid = 2 o-tiles x 128 b-chunks(128 b) = 256 blocks; thread owns one o.
// ---------------------------------------------------------------------------
__global__ __launch_bounds__(256, 2) void k_fwd2p(
    const float* __restrict__ act, const float* __restrict__ w2,
    float* __restrict__ out, float* __restrict__ corr2_part,
    float* __restrict__ outsum_part) {
  const int tid = threadIdx.x;
  const int o = (blockIdx.x & 1) * 256 + tid;
  const int chunk = blockIdx.x >> 1;
  const int b0 = chunk * 128;

  __shared__ float act_s[128][HID];
  {
    const float4* ag = (const float4*)(act + (size_t)b0 * HID);
    float4* as = (float4*)(&act_s[0][0]);
#pragma unroll
    for (int q = 0; q < 4; ++q) as[tid + 256 * q] = ag[tid + 256 * q];
  }

  const float4* w2p = (const float4*)(w2 + (size_t)o * HID);
  float4 w0 = w2p[0], w1r = w2p[1], w2r_ = w2p[2], w3 = w2p[3];
  float4 w4 = w2p[4], w5 = w2p[5], w6 = w2p[6], w7 = w2p[7];

  float4 s0{0,0,0,0}, s1{0,0,0,0}, s2{0,0,0,0}, s3{0,0,0,0};
  float4 s4{0,0,0,0}, s5{0,0,0,0}, s6{0,0,0,0}, s7{0,0,0,0};
  float osum = 0.f;

  __syncthreads();
  for (int b = 0; b < 128; ++b) {
    const float4* ar = (const float4*)(&act_s[b][0]);
    float4 a0 = ar[0], a1 = ar[1], a2 = ar[2], a3 = ar[3];
    float4 a4 = ar[4], a5 = ar[5], a6 = ar[6], a7 = ar[7];
    float z = 0.f;
    DOT4(z, a0, w0); DOT4(z, a1, w1r); DOT4(z, a2, w2r_); DOT4(z, a3, w3);
    DOT4(z, a4, w4); DOT4(z, a5, w5);  DOT4(z, a6, w6);   DOT4(z, a7, w7);
    float ov = 1.0f / (1.0f + __expf(-z)) - 0.4f;
    out[(size_t)(b0 + b) * OUTD + o] = ov;
    osum += ov;
    UPD4(s0, a0, ov); UPD4(s1, a1, ov); UPD4(s2, a2, ov); UPD4(s3, a3, ov);
    UPD4(s4, a4, ov); UPD4(s5, a5, ov); UPD4(s6, a6, ov); UPD4(s7, a7, ov);
  }

  float* c = corr2_part + (size_t)chunk * (HID * OUTD) + o;
  c[0 * OUTD]  = s0.x; c[1 * OUTD]  = s0.y; c[2 * OUTD]  = s0.z; c[3 * OUTD]  = s0.w;
  c[4 * OUTD]  = s1.x; c[5 * OUTD]  = s1.y; c[6 * OUTD]  = s1.z; c[7 * OUTD]  = s1.w;
  c[8 * OUTD]  = s2.x; c[9 * OUTD]  = s2.y; c[10 * OUTD] = s2.z; c[11 * OUTD] = s2.w;
  c[12 * OUTD] = s3.x; c[13 * OUTD] = s3.y; c[14 * OUTD] = s3.z; c[15 * OUTD] = s3.w;
  c[16 * OUTD] = s4.x; c[17 * OUTD] = s4.y; c[18 * OUTD] = s4.z; c[19 * OUTD] = s4.w;
  c[20 * OUTD] = s5.x; c[21 * OUTD] = s5.y; c[22 * OUTD] = s5.z; c[23 * OUTD] = s5.w;
  c[24 * OUTD] = s6.x; c[25 * OUTD] = s6.y; c[26 * OUTD] = s6.z; c[27 * OUTD] = s6.w;
  c[28 * OUTD] = s7.x; c[29 * OUTD] = s7.y; c[30 * OUTD] = s7.z; c[31 * OUTD] = s7.w;
  outsum_part[(size_t)chunk * OUTD + o] = osum;
}

// ---------------------------------------------------------------------------
// K3b: deterministic reduce of corr2/outsum partials. grid = 64 x 256.
// ---------------------------------------------------------------------------
__global__ __launch_bounds__(256) void k_red2(
    const float* __restrict__ corr2_part, const float* __restrict__ outsum_part,
    float* __restrict__ corr2, float* __restrict__ outsum) {
  const int e = blockIdx.x * 256 + threadIdx.x;  // < 16384
  float s = 0.f;
#pragma unroll 8
  for (int c = 0; c < C2; ++c) s += corr2_part[(size_t)c * (HID * OUTD) + e];
  corr2[e] = s;
  if (e < OUTD) {
    float t = 0.f;
#pragma unroll 8
    for (int c = 0; c < C2; ++c) t += outsum_part[(size_t)c * OUTD + e];
    outsum[e] = t;
  }
}

// ---------------------------------------------------------------------------
// K4: w1_new[h,i] = (w1[h,i] + dw1T[i,h]) / ||row h||_2
// ---------------------------------------------------------------------------
__global__ __launch_bounds__(256) void k_w1(
    const float* __restrict__ w1, const float* __restrict__ heb,
    const float* __restrict__ corr1, const float* __restrict__ xsum,
    const float* __restrict__ actsum, float* __restrict__ w1out) {
  const int h = blockIdx.x;
  const int tid = threadIdx.x;
  const float ash = actsum[h];
  const float4* heb4 = (const float4*)heb;

  float val[8];
  float ss = 0.f;
#pragma unroll
  for (int r = 0; r < 8; ++r) {
    const int i = tid + 256 * r;
    float4 c = heb4[(size_t)i * HID + h];
    float v = w1[(size_t)h * IND + i] + 16384.0f * c.w +
              c.x * corr1[(size_t)i * HID + h] + c.y * xsum[i] + c.z * ash;
    val[r] = v;
    ss += v * v;
  }

  __shared__ float red[256];
  red[tid] = ss;
  __syncthreads();
  for (int s = 128; s > 0; s >>= 1) {
    if (tid < s) red[tid] += red[tid + s];
    __syncthreads();
  }
  const float inv = 1.0f / sqrtf(red[0]);
#pragma unroll
  for (int r = 0; r < 8; ++r) {
    const int i = tid + 256 * r;
    w1out[(size_t)h * IND + i] = val[r] * inv;
  }
}

// ---------------------------------------------------------------------------
// K5: w2_new[o,h] = (w2[o,h] + dw2T[h,o]) / ||row o||_2
// ---------------------------------------------------------------------------
__global__ __launch_bounds__(256) void k_w2(
    const float* __restrict__ w2, const float* __restrict__ heb,
    const float* __restrict__ corr2, const float* __restrict__ actsum,
    const float* __restrict__ outsum, float* __restrict__ w2out) {
  const int o = blockIdx.x * 256 + threadIdx.x;
  const float oso = outsum[o];
  const float4* heb4 = (const float4*)heb;

  float val[HID];
  float ss = 0.f;
#pragma unroll
  for (int h = 0; h < HID; ++h) {
    float4 c = heb4[(size_t)(HID * IND) + (size_t)h * OUTD + o];
    float v = w2[(size_t)o * HID + h] + 16384.0f * c.w +
              c.x * corr2[(size_t)h * OUTD + o] + c.y * actsum[h] + c.z * oso;
    val[h] = v;
    ss += v * v;
  }
  const float inv = 1.0f / sqrtf(ss);
#pragma unroll
  for (int h = 0; h < HID; ++h) w2out[(size_t)o * HID + h] = val[h] * inv;
}

// ---------------------------------------------------------------------------
extern "C" void kernel_launch(void* const* d_in, const int* in_sizes, int n_in,
                              void* d_out, int out_size, void* d_ws,
                              size_t ws_size, hipStream_t stream) {
  const float* x   = (const float*)d_in[0];   // [16384, 2048]
  const float* w1  = (const float*)d_in[1];   // [32, 2048]
  const float* w2  = (const float*)d_in[2];   // [512, 32]
  const float* heb = (const float*)d_in[3];   // [81920, 4]

  float* out = (float*)d_out;                 // [16384, 512]
  float* w1o = out + (size_t)BATCH * OUTD;    // [32, 2048]
  float* w2o = w1o + (size_t)HID * IND;       // [512, 32]

  float* ws = (float*)d_ws;
  float* act         = ws;                                     // 524288
  float* corr1       = act + (size_t)BATCH * HID;              // 65536
  float* corr2       = corr1 + (size_t)IND * HID;              // 16384
  float* xsum        = corr2 + (size_t)HID * OUTD;             // 2048
  float* actsum      = xsum + IND;                             // 32
  float* outsum      = actsum + HID;                           // 512
  float* corr1_part  = outsum + OUTD;                          // 64*65536
  float* xsum_part   = corr1_part + (size_t)C1 * IND * HID;    // 64*2048
  float* corr2_part  = xsum_part + (size_t)C1 * IND;           // 128*16384
  float* outsum_part = corr2_part + (size_t)C2 * HID * OUTD;   // 128*512
  float* actsum_part = outsum_part + (size_t)C2 * OUTD;        // 512*32
  // act_part (4*524288 floats) aliases corr1_part (4.19M floats): consumed
  // by k_act_c before k_corr1p overwrites the region.
  float* act_part    = corr1_part;

  k_act_q <<<1024, 256, 0, stream>>>(x, w1, act_part);
  k_act_c <<<512, 256, 0, stream>>>(act_part, act, actsum_part);
  k_corr1p<<<256, 256, 0, stream>>>(x, act, corr1_part, xsum_part);
  k_red1  <<<256, 256, 0, stream>>>(corr1_part, xsum_part, actsum_part,
                                    corr1, xsum, actsum);
  k_fwd2p <<<256, 256, 0, stream>>>(act, w2, out, corr2_part, outsum_part);
  k_red2  <<<64, 256, 0, stream>>>(corr2_part, outsum_part, corr2, outsum);
  k_w1    <<<32, 256, 0, stream>>>(w1, heb, corr1, xsum, actsum, w1o);
  k_w2    <<<2, 256, 0, stream>>>(w2, heb, corr2, actsum, outsum, w2o);
}